// Round 17
// baseline (272.341 us; speedup 1.0000x reference)
//
#include <hip/hip_runtime.h>
#include <math.h>

#define ALPHA   0.99f
#define ONE_M   0.01f     // 1 - ALPHA
#define T_LEN   4000
#define F_DIM   64
#define TT      160       // time rows per tile
#define NTILE   25        // T_LEN / TT
#define LTC     5         // chunk length (rows per chunk)
#define NC      32        // chunks per tile (8 worker waves x 4)
#define NPC     5         // coop pieces per worker thread
#define NWT     512       // worker threads (8 waves)
#define NTHREADS 576      // + 1 dedicated combine wave
#define ROWF    68        // slab row stride in floats (272 B)
#define SLABF   (20 * ROWF)   // floats per wave-private slab

typedef float f32x4 __attribute__((ext_vector_type(4)));

// Block barrier WITHOUT vmcnt drain (global ops stay in flight).
#define LGKM_BAR()                                                    \
  do { asm volatile("s_waitcnt lgkmcnt(0)" ::: "memory");             \
       __builtin_amdgcn_sched_barrier(0);                             \
       __builtin_amdgcn_s_barrier();                                  \
       __builtin_amdgcn_sched_barrier(0); } while (0)

// Intra-wave LDS fence: orders cross-lane ds_write->ds_read within a wave
// (invisible to per-thread alias analysis — R12 lesson).
#define WAVE_FENCE()                                                  \
  do { asm volatile("s_waitcnt lgkmcnt(0)" ::: "memory");             \
       __builtin_amdgcn_sched_barrier(0); } while (0)

// Pipelined body, iteration ii (0..NTILE inclusive):
//   wave 8 : combine(ii)          [summaries -> entering states, SUMC=sum[ii%2]]
//   workers: P4/P5 replay+store tile ii-1  [vX regs + entering from SUMP]
//            P1/P2 transpose+summarize tile ii+1 [vN -> slab -> VX, SUMP]
//            P0 issue nontemporal loads tile ii+2 -> vN
// ONE block barrier per iteration (at top). SUMC/SUMP parity-disjoint.
#define BODY(VX, SMC, SPC, SUC, SMP, SPP, SUP, ii)                          \
  {                                                                         \
    LGKM_BAR();                                                             \
    if (tid >= NWT) {                                                       \
      /* ---- combine wave: serial chain over NC chunks of tile ii ---- */  \
      if ((ii) < NTILE) {                                                   \
        float mu = cmu, var = cvar;                                         \
        for (int cc = 0; cc < NC; ++cc) {                                   \
          float mm = SMC[cc * F_DIM + f8];                                  \
          float pp = SPC[cc * F_DIM + f8];                                  \
          float uu = SUC[cc * F_DIM + f8];                                  \
          SMC[cc * F_DIM + f8] = mu;          /* entering state */          \
          SPC[cc * F_DIM + f8] = var;                                       \
          float mun = AL * mu + mm;                                         \
          var = AL * var + pp + (C2 * uu) * mu + RR * mu * mu;              \
          mu = mun;                                                         \
        }                                                                   \
        cmu = mu; cvar = var;                                               \
      }                                                                     \
    } else {                                                                \
      if ((ii) > 0) {                                                       \
        /* P4: replay tile ii-1 from VX regs + entering(ii-1) */            \
        f32x4 mu2  = *(const f32x4*)&SMP[c * F_DIM + g * 4];                \
        f32x4 var2 = *(const f32x4*)&SPP[c * F_DIM + g * 4];                \
        _Pragma("unroll")                                                   \
        for (int j = 0; j < LTC; ++j) {                                     \
          f32x4 xi = VX[j];                                                 \
          mu2 = ALPHA * mu2 + ONE_M * xi;                                   \
          f32x4 d = xi - mu2;                                               \
          var2 = ALPHA * var2 + ONE_M * (d * d);                            \
          f32x4 o;                                                          \
          o[0] = d[0] * __builtin_amdgcn_rsqf(var2[0]);                     \
          o[1] = d[1] * __builtin_amdgcn_rsqf(var2[1]);                     \
          o[2] = d[2] * __builtin_amdgcn_rsqf(var2[2]);                     \
          o[3] = d[3] * __builtin_amdgcn_rsqf(var2[3]);                     \
          *(f32x4*)&slab[(LTC * cl + j) * ROWF + g * 4] = o;                \
        }                                                                   \
        WAVE_FENCE();   /* cross-lane: P4 writes -> P5 reads */             \
        /* P5: coop read-back + contiguous 1KB nontemporal stores */        \
        _Pragma("unroll")                                                   \
        for (int r = 0; r < NPC; ++r) {                                     \
          f32x4 oc = *(const f32x4*)&slab[(4 * r + cl) * ROWF + g * 4];     \
          __builtin_nontemporal_store(oc,                                   \
              (f32x4*)(out + bbase + (size_t)((ii) - 1) * TT * F_DIM        \
                       + woff + (size_t)r * 256 + (size_t)lw * 4));         \
        }                                                                   \
        WAVE_FENCE();   /* P5 reads done before P1 overwrites */            \
      }                                                                     \
      if ((ii) + 1 < NTILE) {                                               \
        /* P1: vN (tile ii+1, loads in flight) -> own slab */               \
        _Pragma("unroll")                                                   \
        for (int r = 0; r < NPC; ++r)                                       \
          *(f32x4*)&slab[(4 * r + cl) * ROWF + g * 4] = vN[r];              \
        WAVE_FENCE();   /* cross-lane: P1 writes -> P2 reads */             \
        /* P0: issue loads for tile ii+2 */                                 \
        if ((ii) + 2 < NTILE) {                                             \
          _Pragma("unroll")                                                 \
          for (int r = 0; r < NPC; ++r)                                     \
            vN[r] = __builtin_nontemporal_load(                             \
                (const f32x4*)(x + bbase + (size_t)((ii) + 2) * TT * F_DIM  \
                               + woff + (size_t)r * 256 + (size_t)lw * 4)); \
        }                                                                   \
        /* P2: chunk rows -> VX; pass-1 sums; summaries -> SUMP */          \
        {                                                                   \
          f32x4 m = 0.f, sp = 0.f, su = 0.f;                                \
          _Pragma("unroll")                                                 \
          for (int j = 0; j < LTC; ++j) {                                   \
            VX[j] = *(const f32x4*)&slab[(LTC * cl + j) * ROWF + g * 4];    \
            f32x4 xi = VX[j];                                               \
            m = ALPHA * m + ONE_M * xi;                                     \
            f32x4 u = xi - m;                                               \
            sp = ALPHA * sp + ONE_M * (u * u);                              \
            su = su + u;                                                    \
          }                                                                 \
          *(f32x4*)&SMP[c * F_DIM + g * 4] = m;                             \
          *(f32x4*)&SPP[c * F_DIM + g * 4] = sp;                            \
          *(f32x4*)&SUP[c * F_DIM + g * 4] = su;                            \
        }                                                                   \
      }                                                                     \
    }                                                                       \
  }

// Exact chunked scan per (b,f):  mu_L = a^L mu_0 + m_L ;
//   var_L = a^L var_0 + SP + c2*SU*mu_0 + R*mu_0^2   (L = LTC = 5)
// x read once (nontemporal), out written once (nontemporal), all global
// traffic contiguous 1KB/wave. Dedicated combine wave overlaps the serial
// chain with the workers' streaming; 1 barrier per tile.
__global__ __launch_bounds__(NTHREADS, 3)
void erbnorm_kernel(const float* __restrict__ x, float* __restrict__ out, float aL) {
    const int b   = blockIdx.x;
    const int tid = threadIdx.x;
    const int w   = tid >> 6;          // wave 0..8
    const int lw  = tid & 63;          // lane in wave
    const int c   = tid >> 4;          // worker global chunk 0..31
    const int cl  = (tid >> 4) & 3;    // chunk-local within wave
    const int g   = tid & 15;          // float4 group 0..15
    const int f8  = tid & 63;          // combine-wave feature index
    const size_t woff = (size_t)w * 1280;   // worker wave's float offset in tile

    const float AL = aL;
    const float C2 = -2.f * ONE_M * aL;        // -2(1-a)a^L
    const float RR = ALPHA * aL * (1.f - aL);  // a^(L+1)(1-a^L)

    __shared__ __align__(16) float lds_img[8 * SLABF];        // 43,520 B
    __shared__ float s_m0[NC * F_DIM], s_sp0[NC * F_DIM], s_su0[NC * F_DIM];
    __shared__ float s_m1[NC * F_DIM], s_sp1[NC * F_DIM], s_su1[NC * F_DIM];
    float* slab = &lds_img[(w < 8 ? w : 0) * SLABF];

    const size_t bbase = (size_t)b * T_LEN * F_DIM;

    // combine-chain state (wave 8, lane f8)
    float cmu  = -60.f + (float)f8 * (-30.f / 63.f);
    float cvar = 1600.f;

    f32x4 vN[NPC];          // coop pieces of next tile (loads in flight)
    f32x4 vxE[LTC], vxO[LTC];   // chunk rows, double-buffered by tile parity

    // ---- prologue (workers): tile 0 load+transpose+summarize -> sum0/vxE;
    //      issue tile 1 loads ----
    if (tid < NWT) {
#pragma unroll
        for (int r = 0; r < NPC; ++r)
            vN[r] = __builtin_nontemporal_load(
                (const f32x4*)(x + bbase + woff + (size_t)r * 256 + (size_t)lw * 4));
#pragma unroll
        for (int r = 0; r < NPC; ++r)
            *(f32x4*)&slab[(4 * r + cl) * ROWF + g * 4] = vN[r];
        WAVE_FENCE();
        {
            f32x4 m = 0.f, sp = 0.f, su = 0.f;
#pragma unroll
            for (int j = 0; j < LTC; ++j) {
                vxE[j] = *(const f32x4*)&slab[(LTC * cl + j) * ROWF + g * 4];
                f32x4 xi = vxE[j];
                m = ALPHA * m + ONE_M * xi;
                f32x4 u = xi - m;
                sp = ALPHA * sp + ONE_M * (u * u);
                su = su + u;
            }
            *(f32x4*)&s_m0 [c * F_DIM + g * 4] = m;
            *(f32x4*)&s_sp0[c * F_DIM + g * 4] = sp;
            *(f32x4*)&s_su0[c * F_DIM + g * 4] = su;
        }
#pragma unroll
        for (int r = 0; r < NPC; ++r)
            vN[r] = __builtin_nontemporal_load(
                (const f32x4*)(x + bbase + (size_t)TT * F_DIM
                               + woff + (size_t)r * 256 + (size_t)lw * 4));
    }

    // ---- pipelined main loop: iterations 0..NTILE (26 bodies, 13 pairs) ----
    for (int i2 = 0; i2 <= NTILE; i2 += 2) {
        BODY(vxO, s_m0, s_sp0, s_su0, s_m1, s_sp1, s_su1, i2);
        BODY(vxE, s_m1, s_sp1, s_su1, s_m0, s_sp0, s_su0, i2 + 1);
    }
}

extern "C" void kernel_launch(void* const* d_in, const int* in_sizes, int n_in,
                              void* d_out, int out_size, void* d_ws, size_t ws_size,
                              hipStream_t stream) {
    const float* x = (const float*)d_in[0];
    float* out = (float*)d_out;
    const float aL = (float)pow(0.99, (double)LTC);  // a^5
    hipLaunchKernelGGL(erbnorm_kernel, dim3(256), dim3(NTHREADS), 0, stream,
                       x, out, aL);
}

// Round 18
// 103.057 us; speedup vs baseline: 2.6426x; 2.6426x over previous
//
#include <hip/hip_runtime.h>
#include <math.h>

#define ALPHA   0.99f
#define ONE_M   0.01f     // 1 - ALPHA
#define T_LEN   4000
#define F_DIM   64
#define TT      160       // time rows per tile
#define NTILE   25        // T_LEN / TT
#define LTC     5         // chunk length (rows per chunk)
#define NC      32        // chunks per tile (8 waves x 4)
#define NPC     5         // coop pieces per thread
#define NTHREADS 512      // 8 waves
#define ROWF    68        // slab row stride in floats (272 B)
#define SLABF   (20 * ROWF)   // floats per wave-private slab
#define CB      8         // combine batch size (NC/4)

typedef float f32x4 __attribute__((ext_vector_type(4)));

// Block barrier WITHOUT vmcnt drain: LDS visibility only; global loads/stores
// stay in flight across it.
#define LGKM_BAR()                                                    \
  do { asm volatile("s_waitcnt lgkmcnt(0)" ::: "memory");             \
       __builtin_amdgcn_sched_barrier(0);                             \
       __builtin_amdgcn_s_barrier();                                  \
       __builtin_amdgcn_sched_barrier(0); } while (0)

// Intra-wave LDS fence (no s_barrier): orders cross-lane ds_write->ds_read
// within the wave, invisible to per-thread alias analysis (R12 lesson).
#define WAVE_FENCE()                                                  \
  do { asm volatile("s_waitcnt lgkmcnt(0)" ::: "memory");             \
       __builtin_amdgcn_sched_barrier(0); } while (0)

// One tile (R16 structure; only P3 changed to batched-prefetch combine).
#define TILE_BODY(VC, VN, kk)                                               \
  {                                                                         \
    const size_t tb = bbase + (size_t)(kk) * TT * F_DIM;                    \
    /* P0: issue next tile's coop loads first (VN dead; deepest overlap) */ \
    if ((kk) + 1 < NTILE) {                                                 \
      _Pragma("unroll")                                                     \
      for (int r = 0; r < NPC; ++r)                                         \
        VN[r] = __builtin_nontemporal_load(                                 \
            (const f32x4*)(x + tb + (size_t)TT * F_DIM + woff               \
                           + (size_t)r * 256 + (size_t)lw * 4));            \
    }                                                                       \
    /* P1: coop pieces -> own slab (slab row 4r + cl); VC dead after */     \
    _Pragma("unroll")                                                       \
    for (int r = 0; r < NPC; ++r)                                           \
      *(f32x4*)&slab[(4 * r + cl) * ROWF + g * 4] = VC[r];                  \
    WAVE_FENCE();   /* cross-lane RAW: P1 writes -> P2 reads */             \
    /* P2: chunk-layout reads into vX; pass-1 sums; summaries */            \
    f32x4 vX[LTC];                                                          \
    {                                                                       \
      f32x4 m = 0.f, sp = 0.f, su = 0.f;                                    \
      _Pragma("unroll")                                                     \
      for (int j = 0; j < LTC; ++j) {                                       \
        vX[j] = *(const f32x4*)&slab[(LTC * cl + j) * ROWF + g * 4];        \
        f32x4 xi = vX[j];                                                   \
        m = ALPHA * m + ONE_M * xi;                                         \
        f32x4 u = xi - m;                                                   \
        sp = ALPHA * sp + ONE_M * (u * u);                                  \
        su = su + u;                                                        \
      }                                                                     \
      *(f32x4*)&s_m [c * F_DIM + g * 4] = m;                                \
      *(f32x4*)&s_sp[c * F_DIM + g * 4] = sp;                               \
      *(f32x4*)&s_su[c * F_DIM + g * 4] = su;                               \
    }                                                                       \
    LGKM_BAR();   /* BAR1: all summaries visible */                         \
    /* P3: combine — batched: prefetch 8 chunks' params into regs (the 24  */\
    /* LDS reads pipeline), then 8 register-only chain steps. Exposed LDS  */\
    /* latency per tile: 4x instead of 32x.                                */\
    if (tid < F_DIM) {                                                      \
      float mu = cmu, var = cvar;                                           \
      for (int cb = 0; cb < NC / CB; ++cb) {                                \
        float mm[CB], pp[CB], uu[CB];                                       \
        _Pragma("unroll")                                                   \
        for (int q = 0; q < CB; ++q) {                                      \
          const int cc = cb * CB + q;                                       \
          mm[q] = s_m [cc * F_DIM + tid];                                   \
          pp[q] = s_sp[cc * F_DIM + tid];                                   \
          uu[q] = s_su[cc * F_DIM + tid];                                   \
        }                                                                   \
        _Pragma("unroll")                                                   \
        for (int q = 0; q < CB; ++q) {                                      \
          const int cc = cb * CB + q;                                       \
          s_m [cc * F_DIM + tid] = mu;        /* entering state */          \
          s_sp[cc * F_DIM + tid] = var;                                     \
          float mun = AL * mu + mm[q];                                      \
          var = AL * var + pp[q] + (C2 * uu[q]) * mu + RR * mu * mu;        \
          mu = mun;                                                         \
        }                                                                   \
      }                                                                     \
      cmu = mu; cvar = var;                                                 \
    }                                                                       \
    LGKM_BAR();   /* BAR2: entering states visible; WAR vs next summaries */\
    /* P4: entering state; pass-2 from vX registers; o -> slab chunk rows */\
    {                                                                       \
      f32x4 mu2  = *(const f32x4*)&s_m [c * F_DIM + g * 4];                 \
      f32x4 var2 = *(const f32x4*)&s_sp[c * F_DIM + g * 4];                 \
      _Pragma("unroll")                                                     \
      for (int j = 0; j < LTC; ++j) {                                       \
        f32x4 xi = vX[j];                                                   \
        mu2 = ALPHA * mu2 + ONE_M * xi;                                     \
        f32x4 d = xi - mu2;                                                 \
        var2 = ALPHA * var2 + ONE_M * (d * d);                              \
        f32x4 o;                                                            \
        o[0] = d[0] * __builtin_amdgcn_rsqf(var2[0]);                       \
        o[1] = d[1] * __builtin_amdgcn_rsqf(var2[1]);                       \
        o[2] = d[2] * __builtin_amdgcn_rsqf(var2[2]);                       \
        o[3] = d[3] * __builtin_amdgcn_rsqf(var2[3]);                       \
        *(f32x4*)&slab[(LTC * cl + j) * ROWF + g * 4] = o;                  \
      }                                                                     \
    }                                                                       \
    WAVE_FENCE();   /* cross-lane RAW: P4 writes -> P5 reads */             \
    /* P5: coop read-back from own slab + contiguous 1KB nontemporal stores*/\
    _Pragma("unroll")                                                       \
    for (int r = 0; r < NPC; ++r) {                                         \
      f32x4 oc = *(const f32x4*)&slab[(4 * r + cl) * ROWF + g * 4];         \
      __builtin_nontemporal_store(oc,                                       \
          (f32x4*)(out + tb + woff + (size_t)r * 256 + (size_t)lw * 4));    \
    }                                                                       \
    WAVE_FENCE();   /* P5 reads done before next tile's P1 overwrites */    \
  }

// Exact chunked scan per (b,f):
//   mu_L  = a^L mu_0 + m_L
//   var_L = a^L var_0 + SP + c2*SU*mu_0 + R*mu_0^2   (L = LTC = 5)
// x read from HBM exactly once; every global wave instruction is one
// contiguous aligned 1 KB segment (wave-private 20-row slab transposes
// coop-linear <-> chunk layout). 2 block barriers per tile.
__global__ __launch_bounds__(NTHREADS, 2)
void erbnorm_kernel(const float* __restrict__ x, float* __restrict__ out, float aL) {
    const int b   = blockIdx.x;
    const int tid = threadIdx.x;
    const int w   = tid >> 6;          // wave 0..7
    const int lw  = tid & 63;          // lane in wave
    const int c   = tid >> 4;          // global chunk 0..31 (= 4w + cl)
    const int cl  = (tid >> 4) & 3;    // chunk-local within wave
    const int g   = tid & 15;          // float4 group 0..15
    const size_t woff = (size_t)w * 1280;   // wave's float offset in tile

    const float AL = aL;
    const float C2 = -2.f * ONE_M * aL;        // -2(1-a)a^L
    const float RR = ALPHA * aL * (1.f - aL);  // a^(L+1)(1-a^L)

    __shared__ __align__(16) float lds_img[8 * SLABF];        // 43,520 B
    __shared__ float s_m [NC * F_DIM];                        //  8,192 B
    __shared__ float s_sp[NC * F_DIM];                        //  8,192 B
    __shared__ float s_su[NC * F_DIM];                        //  8,192 B
    float* slab = &lds_img[w * SLABF];

    const size_t bbase = (size_t)b * T_LEN * F_DIM;

    // combine-chain state (meaningful for tid < 64)
    float cmu  = -60.f + (float)tid * (-30.f / 63.f);
    float cvar = 1600.f;

    f32x4 vA[NPC], vB[NPC];
    // prologue: tile 0, coop-linear (wave-private 20-row block)
#pragma unroll
    for (int r = 0; r < NPC; ++r)
        vA[r] = __builtin_nontemporal_load(
            (const f32x4*)(x + bbase + woff + (size_t)r * 256 + (size_t)lw * 4));

    for (int k2 = 0; k2 < NTILE - 1; k2 += 2) {   // 12 pairs: tiles 0..23
        TILE_BODY(vA, vB, k2);
        TILE_BODY(vB, vA, k2 + 1);
    }
    TILE_BODY(vA, vB, NTILE - 1);                 // tail tile 24 (no prefetch)
}

extern "C" void kernel_launch(void* const* d_in, const int* in_sizes, int n_in,
                              void* d_out, int out_size, void* d_ws, size_t ws_size,
                              hipStream_t stream) {
    const float* x = (const float*)d_in[0];
    float* out = (float*)d_out;
    const float aL = (float)pow(0.99, (double)LTC);  // a^5
    hipLaunchKernelGGL(erbnorm_kernel, dim3(256), dim3(NTHREADS), 0, stream,
                       x, out, aL);
}